// Round 2
// baseline (124.976 us; speedup 1.0000x reference)
//
#include <hip/hip_runtime.h>

#define DIM   256
#define NQ    8
#define EMBED 512
#define FFN   2048
#define ROWS  (4 * 8192)             // B*S = 32768
#define OUT_ELEMS (ROWS * EMBED)     // 16777216 fp32
#define OUT_VEC4  (EMBED / 4)        // 128 float4 per row
#define OUT_TOTAL4 (OUT_ELEMS / 4)   // 4194304 float4

#define BBLOCKS 1024
#define BTHREADS (BBLOCKS * 256)     // 262144, % 128 == 0 -> column invariant
#define BITERS  (OUT_TOTAL4 / BTHREADS)  // 16

// native clang vector type — __builtin_nontemporal_store rejects the
// HIP_vector_type<float,4> class; it accepts true vector types.
typedef float fvec4 __attribute__((ext_vector_type(4)));

// Kernel A: one block per output embedding e (512 blocks, 256 threads).
// Each block REDUNDANTLY computes z (from |U[:,0]|^2 marginals) and
// h = relu(W1 z + b1) — W1/U reads are L2 hits after the first block —
// then ov[e] = dot(W2[e,:], h) + b2[e].
// v2: W2 row + b2 loads hoisted to the top so their HBM-miss latency
// (~900 cyc cold) hides under the z-reduce + h-compute; one barrier removed.
__global__ __launch_bounds__(256) void k_ov(const float* __restrict__ U_re,
                                            const float* __restrict__ U_im,
                                            const float* __restrict__ W1,
                                            const float* __restrict__ b1,
                                            const float* __restrict__ W2,
                                            const float* __restrict__ b2,
                                            float* __restrict__ ov) {
    int t = threadIdx.x;
    int e = blockIdx.x;

    // ---- issue the cold HBM loads FIRST (consumed only at the end) ----
    const float4* row = (const float4*)(W2 + (size_t)e * FFN);  // 8KB row
    float4 a0 = row[t];
    float4 a1 = row[256 + t];
    float bb = b2[e];            // uniform -> scalar load

    // ---- probs for this thread's basis state k = t ----
    float re = U_re[t * DIM];    // column 0, stride DIM
    float im = U_im[t * DIM];
    float p  = re * re + im * im;

    // ---- z[q] = sum_k sign(bit(7-q) of k) * p[k], block-parallel ----
    float zp[NQ];
#pragma unroll
    for (int q = 0; q < NQ; ++q)
        zp[q] = ((t >> (NQ - 1 - q)) & 1) ? -p : p;
#pragma unroll
    for (int off = 32; off > 0; off >>= 1) {
#pragma unroll
        for (int q = 0; q < NQ; ++q)
            zp[q] += __shfl_down(zp[q], off, 64);
    }
    __shared__ float zw[4][NQ];
    if ((t & 63) == 0) {
#pragma unroll
        for (int q = 0; q < NQ; ++q) zw[t >> 6][q] = zp[q];
    }
    __syncthreads();

    // every thread sums the 4 wave partials directly (LDS broadcast reads);
    // saves the t<8 stage + second barrier of v1.
    float zr[NQ];
#pragma unroll
    for (int q = 0; q < NQ; ++q)
        zr[q] = zw[0][q] + zw[1][q] + zw[2][q] + zw[3][q];

    // ---- h = relu(W1 z + b1) into LDS (each thread does 8 rows) ----
    __shared__ float h[FFN];
#pragma unroll
    for (int r = 0; r < FFN / 256; ++r) {
        int f = r * 256 + t;
        const float4* w = (const float4*)(W1 + f * NQ);  // 32B-aligned row
        float4 w0 = w[0], w1 = w[1];
        float acc = b1[f];
        acc += zr[0] * w0.x + zr[1] * w0.y + zr[2] * w0.z + zr[3] * w0.w;
        acc += zr[4] * w1.x + zr[5] * w1.y + zr[6] * w1.z + zr[7] * w1.w;
        h[f] = fmaxf(acc, 0.f);
    }
    __syncthreads();

    // ---- ov[e] = dot(W2[e,:], h) + b2[e] (a0/a1 already in flight) ----
    const float4* h4 = (const float4*)h;
    float4 hb0 = h4[t];
    float4 hb1 = h4[256 + t];
    float acc = a0.x * hb0.x + a0.y * hb0.y + a0.z * hb0.z + a0.w * hb0.w
              + a1.x * hb1.x + a1.y * hb1.y + a1.z * hb1.z + a1.w * hb1.w;
#pragma unroll
    for (int off = 32; off > 0; off >>= 1)
        acc += __shfl_down(acc, off, 64);
    __shared__ float wsum[4];
    if ((t & 63) == 0) wsum[t >> 6] = acc;
    __syncthreads();
    if (t == 0)
        ov[e] = wsum[0] + wsum[1] + wsum[2] + wsum[3] + bb;
}

// Kernel B: broadcast ov (512 floats) to all 32768 rows of out.
// 1024 blocks x 256 threads; thread stride 262144 % 128 == 0 -> each
// thread's float4-column (tid & 127) is invariant: load ov once, emit 16
// fully-unrolled nontemporal float4 stores (bypass L2: out is write-once,
// never re-read -> no dirty-L2 writeback tail).
__global__ __launch_bounds__(256) void k_broadcast(const float* __restrict__ ov,
                                                   float* __restrict__ out) {
    int tid = blockIdx.x * 256 + threadIdx.x;
    const float4 vv = ((const float4*)ov)[tid & (OUT_VEC4 - 1)];
    fvec4 v = { vv.x, vv.y, vv.z, vv.w };
    fvec4* o = (fvec4*)out + tid;
#pragma unroll
    for (int i = 0; i < BITERS; ++i)
        __builtin_nontemporal_store(v, o + i * BTHREADS);
}

extern "C" void kernel_launch(void* const* d_in, const int* in_sizes, int n_in,
                              void* d_out, int out_size, void* d_ws, size_t ws_size,
                              hipStream_t stream) {
    // inputs: x, U_re, U_im, W1, b1, W2, b2  (x is shape-only, unused)
    const float* U_re = (const float*)d_in[1];
    const float* U_im = (const float*)d_in[2];
    const float* W1   = (const float*)d_in[3];
    const float* b1   = (const float*)d_in[4];
    const float* W2   = (const float*)d_in[5];
    const float* b2   = (const float*)d_in[6];
    float* out = (float*)d_out;

    float* ov = (float*)d_ws;    // 512 floats of scratch

    k_ov       <<<EMBED,   256, 0, stream>>>(U_re, U_im, W1, b1, W2, b2, ov);
    k_broadcast<<<BBLOCKS, 256, 0, stream>>>(ov, out);
}

// Round 3
// 120.995 us; speedup vs baseline: 1.0329x; 1.0329x over previous
//
#include <hip/hip_runtime.h>

#define DIM   256
#define NQ    8
#define EMBED 512
#define FFN   2048
#define ROWS  (4 * 8192)             // B*S = 32768
#define OUT_ELEMS (ROWS * EMBED)     // 16777216 fp32
#define OUT_VEC4  (EMBED / 4)        // 128 float4 per row
#define OUT_TOTAL4 (OUT_ELEMS / 4)   // 4194304 float4

// Kernel A: one block per output embedding e (512 blocks, 256 threads).
// Each block REDUNDANTLY computes z (from |U[:,0]|^2 marginals) and
// h = relu(W1 z + b1) — W1/U reads are L2 hits after the first block —
// then ov[e] = dot(W2[e,:], h) + b2[e].
// W2 row + b2 loads hoisted to the top so their HBM-miss latency
// (~900 cyc cold) hides under the z-reduce + h-compute.
__global__ __launch_bounds__(256) void k_ov(const float* __restrict__ U_re,
                                            const float* __restrict__ U_im,
                                            const float* __restrict__ W1,
                                            const float* __restrict__ b1,
                                            const float* __restrict__ W2,
                                            const float* __restrict__ b2,
                                            float* __restrict__ ov) {
    int t = threadIdx.x;
    int e = blockIdx.x;

    // ---- issue the cold HBM loads FIRST (consumed only at the end) ----
    const float4* row = (const float4*)(W2 + (size_t)e * FFN);  // 8KB row
    float4 a0 = row[t];
    float4 a1 = row[256 + t];
    float bb = b2[e];            // uniform -> scalar load

    // ---- probs for this thread's basis state k = t ----
    float re = U_re[t * DIM];    // column 0, stride DIM
    float im = U_im[t * DIM];
    float p  = re * re + im * im;

    // ---- z[q] = sum_k sign(bit(7-q) of k) * p[k], block-parallel ----
    float zp[NQ];
#pragma unroll
    for (int q = 0; q < NQ; ++q)
        zp[q] = ((t >> (NQ - 1 - q)) & 1) ? -p : p;
#pragma unroll
    for (int off = 32; off > 0; off >>= 1) {
#pragma unroll
        for (int q = 0; q < NQ; ++q)
            zp[q] += __shfl_down(zp[q], off, 64);
    }
    __shared__ float zw[4][NQ];
    if ((t & 63) == 0) {
#pragma unroll
        for (int q = 0; q < NQ; ++q) zw[t >> 6][q] = zp[q];
    }
    __syncthreads();

    // every thread sums the 4 wave partials directly (LDS broadcast reads)
    float zr[NQ];
#pragma unroll
    for (int q = 0; q < NQ; ++q)
        zr[q] = zw[0][q] + zw[1][q] + zw[2][q] + zw[3][q];

    // ---- h = relu(W1 z + b1) into LDS (each thread does 8 rows) ----
    __shared__ float h[FFN];
#pragma unroll
    for (int r = 0; r < FFN / 256; ++r) {
        int f = r * 256 + t;
        const float4* w = (const float4*)(W1 + f * NQ);  // 32B-aligned row
        float4 w0 = w[0], w1 = w[1];
        float acc = b1[f];
        acc += zr[0] * w0.x + zr[1] * w0.y + zr[2] * w0.z + zr[3] * w0.w;
        acc += zr[4] * w1.x + zr[5] * w1.y + zr[6] * w1.z + zr[7] * w1.w;
        h[f] = fmaxf(acc, 0.f);
    }
    __syncthreads();

    // ---- ov[e] = dot(W2[e,:], h) + b2[e] (a0/a1 already in flight) ----
    const float4* h4 = (const float4*)h;
    float4 hb0 = h4[t];
    float4 hb1 = h4[256 + t];
    float acc = a0.x * hb0.x + a0.y * hb0.y + a0.z * hb0.z + a0.w * hb0.w
              + a1.x * hb1.x + a1.y * hb1.y + a1.z * hb1.z + a1.w * hb1.w;
#pragma unroll
    for (int off = 32; off > 0; off >>= 1)
        acc += __shfl_down(acc, off, 64);
    __shared__ float wsum[4];
    if ((t & 63) == 0) wsum[t >> 6] = acc;
    __syncthreads();
    if (t == 0)
        ov[e] = wsum[0] + wsum[1] + wsum[2] + wsum[3] + bb;
}

// Kernel B (reverted to the harness-verified 120.8 µs version): broadcast
// ov (512 floats) to all 32768 rows of out with PLAIN float4 stores —
// out (64 MiB) fits the 256 MiB L3, so dirty lines can defer HBM
// writeback past kernel EOP; nontemporal stores forced that traffic
// inside the timed window (R2: +4 µs).
// stride % 128 == 0 -> each thread's column (idx & 127) is invariant:
// load ov once, store 4 float4s, fully coalesced.
__global__ void k_broadcast(const float* __restrict__ ov,
                            float* __restrict__ out) {
    const float4* ov4 = (const float4*)ov;
    float4* out4 = (float4*)out;
    int idx = blockIdx.x * blockDim.x + threadIdx.x;
    int stride = gridDim.x * blockDim.x;   // 4096*256 = 1048576, %128==0
    float4 v = ov4[idx & (OUT_VEC4 - 1)];
    for (; idx < OUT_TOTAL4; idx += stride)
        out4[idx] = v;
}

extern "C" void kernel_launch(void* const* d_in, const int* in_sizes, int n_in,
                              void* d_out, int out_size, void* d_ws, size_t ws_size,
                              hipStream_t stream) {
    // inputs: x, U_re, U_im, W1, b1, W2, b2  (x is shape-only, unused)
    const float* U_re = (const float*)d_in[1];
    const float* U_im = (const float*)d_in[2];
    const float* W1   = (const float*)d_in[3];
    const float* b1   = (const float*)d_in[4];
    const float* W2   = (const float*)d_in[5];
    const float* b2   = (const float*)d_in[6];
    float* out = (float*)d_out;

    float* ov = (float*)d_ws;    // 512 floats of scratch

    k_ov       <<<EMBED, 256, 0, stream>>>(U_re, U_im, W1, b1, W2, b2, ov);
    k_broadcast<<<4096,  256, 0, stream>>>(ov, out);
}